// Round 4
// baseline (103.296 us; speedup 1.0000x reference)
//
#include <hip/hip_runtime.h>

// Sinkhorn (eps=0.2, 50 iters), 64x64 images, b=64. Separable banded Gibbs:
// K = G (x) G, G[i,k]=exp(-5(i-k)^2), radius 2 in fp32. Each K-apply =
// col-conv then row-conv, both in LDS, pitch 65.
//
// Bank math (32 banks): col phase addr = 65m + l      -> bank (l+c)%32, free.
//   row phase thread mapping r = 8*w8 + (l&7), c0 = 8*(l>>3):
//   addr = 65r + c0 + m -> bank = (q + 8hq + c)%32, bijective on each
//   32-lane half -> conflict-free (fixes R3's 2.09M 2-way conflicts).
//
// Two images per 1024-thread block (waves 0-7 image A, 8-15 image B) for
// 4 waves/SIMD latency hiding; chains share barriers symmetrically.
// Two buffers per image: col-conv scratch aliases the dead destination
// buffer. RAW (write S -> read S, same wave) is fenced with lgkmcnt(0);
// WAR (read S -> overwrite with result) is safe because the reads' data is
// consumed by the conv before the writes issue.

#define PT   65
#define IMG  8580     // stride between the two images' buffer sets (floats)

#define FENCE() asm volatile("s_waitcnt lgkmcnt(0)" ::: "memory")

__device__ __forceinline__ float frcp_nr(float d) {
    float r = __builtin_amdgcn_rcpf(d);
    return r * fmaf(-d, r, 2.0f);   // 1 Newton step: ~1 ulp
}

// 12-tap window, column direction (stride PT); edge rows zeroed by select
__device__ __forceinline__ void win_col(const float* __restrict__ rp,
                                        bool lo, bool hi, float* __restrict__ wv) {
#pragma unroll
    for (int m = 0; m < 12; ++m) wv[m] = rp[PT * m];
    wv[0]  = lo ? wv[0]  : 0.0f;  wv[1]  = lo ? wv[1]  : 0.0f;
    wv[10] = hi ? wv[10] : 0.0f;  wv[11] = hi ? wv[11] : 0.0f;
}

// 12-tap window, row direction (stride 1); edge cols zeroed by select
__device__ __forceinline__ void win_row(const float* __restrict__ rp,
                                        bool lo, bool hi, float* __restrict__ wv) {
#pragma unroll
    for (int m = 0; m < 12; ++m) wv[m] = rp[m];
    wv[0]  = lo ? wv[0]  : 0.0f;  wv[1]  = lo ? wv[1]  : 0.0f;
    wv[10] = hi ? wv[10] : 0.0f;  wv[11] = hi ? wv[11] : 0.0f;
}

__device__ __forceinline__ void conv_g(const float* __restrict__ wv,
                                       float g1, float g2, float* __restrict__ o) {
#pragma unroll
    for (int k = 0; k < 8; ++k) {
        float s2 = wv[k] + wv[k + 4], s1 = wv[k + 1] + wv[k + 3];
        o[k] = fmaf(g2, s2, fmaf(g1, s1, wv[k + 2]));
    }
}

__device__ __forceinline__ void conv_q(const float* __restrict__ wv,
                                       float q1, float q2, float* __restrict__ o) {
#pragma unroll
    for (int k = 0; k < 8; ++k) {
        float s2 = wv[k] + wv[k + 4], s1 = wv[k + 1] + wv[k + 3];
        o[k] = fmaf(q2, s2, q1 * s1);
    }
}

extern "C" __global__ void __launch_bounds__(1024)
sinkhorn_kernel(const float* __restrict__ x, const float* __restrict__ y,
                const float* __restrict__ cost, const float* __restrict__ kern,
                float* __restrict__ partials)
{
    // layout: [pad130][V0 4160][pad130][U0 4160][pad130][V1][pad130][U1][pad130][wsum16]
    __shared__ float lds[17312];

    const int t  = threadIdx.x;
    const int l  = t & 63;
    const int w  = t >> 6;        // 0..15
    const int im = w >> 3;        // image within block
    const int w8 = w & 7;         // wave role within image
    const int q  = l & 7;
    const int hq = l >> 3;
    const int r  = 8 * w8 + q;    // row-phase row   (conflict-free mapping)
    const int c0 = 8 * hq;        // row-phase col base
    const int b  = 2 * blockIdx.x + im;

    float* const V    = lds + 130  + im * IMG;
    float* const U    = lds + 4420 + im * IMG;
    float* const wsum = lds + 17290;

    const float g1 = kern[(size_t)64  * 4096];        // e^-5
    const float g2 = kern[(size_t)128 * 4096];        // e^-20
    const float q1 = cost[(size_t)64  * 4096] * g1;   // 1*e^-5
    const float q2 = cost[(size_t)128 * 4096] * g2;   // 4*e^-20

    // loop-invariant LDS pointers (pure ds_* with immediate offsets inside loop)
    float* const pVr1 = V + PT * (8 * w8 - 2) + l;    // col reads from V [PT*m]
    float* const pUr1 = U + PT * (8 * w8 - 2) + l;    // col reads from U [PT*m]
    float* const pVw1 = V + PT * (8 * w8) + l;        // col scratch writes [PT*k]
    float* const pUw1 = U + PT * (8 * w8) + l;
    float* const pV2  = V + PT * r + c0;              // row phase: reads [m-2], writes [k]
    float* const pU2  = U + PT * r + c0;

    const bool wlo = (w8 > 0), whi = (w8 < 7);        // row-edge flags (col phase)
    const bool clo = (hq > 0), chi = (hq < 7);        // col-edge flags (row phase)

    // marginals at the row-phase mapping, registers for all 50 iters
    float xv[8], yv[8];
    {
        const float* xb = x + (size_t)b * 4096 + 64 * r + c0;
        const float* yb = y + (size_t)b * 4096 + 64 * r + c0;
#pragma unroll
        for (int k = 0; k < 8; ++k) xv[k] = xb[k];
#pragma unroll
        for (int k = 0; k < 8; ++k) yv[k] = yb[k];
    }

    // V init = 1/n (conflict-free mapping)
#pragma unroll
    for (int k = 0; k < 8; ++k) pV2[k] = 1.0f / 4096.0f;
    __syncthreads();

    float wv[12], o[8], um[8];

#pragma unroll 1
    for (int it = 0; it < 50; ++it) {
        // ---- pair 1:  S = G*V (col conv, scratch in U);  U = x / (S*G + 1e-8)
        win_col(pVr1, wlo, whi, wv);
        conv_g(wv, g1, g2, o);
#pragma unroll
        for (int k = 0; k < 8; ++k) pUw1[PT * k] = o[k];
        FENCE();
        win_row(pU2 - 2, clo, chi, wv);
        conv_g(wv, g1, g2, o);
#pragma unroll
        for (int k = 0; k < 8; ++k) { um[k] = xv[k] * frcp_nr(o[k] + 1e-8f); pU2[k] = um[k]; }
        __syncthreads();

        // ---- pair 2:  S = G*U (scratch in V);  V = y / (S*G + 1e-8)
        win_col(pUr1, wlo, whi, wv);
        conv_g(wv, g1, g2, o);
#pragma unroll
        for (int k = 0; k < 8; ++k) pVw1[PT * k] = o[k];
        FENCE();
        win_row(pV2 - 2, clo, chi, wv);
        conv_g(wv, g1, g2, o);
#pragma unroll
        for (int k = 0; k < 8; ++k) pV2[k] = yv[k] * frcp_nr(o[k] + 1e-8f);
        __syncthreads();
    }

    // ---- distance: sum U o (G2*V*G) + sum U o (G*V*G2); um = final U (regs)
    // No barriers needed: V is read-only here, scratch rows are wave-private.
    float acc = 0.0f;

    win_col(pVr1, wlo, whi, wv);          // (G2*V) col conv
    conv_q(wv, q1, q2, o);
#pragma unroll
    for (int k = 0; k < 8; ++k) pUw1[PT * k] = o[k];
    FENCE();
    win_row(pU2 - 2, clo, chi, wv);       // *G row conv
    conv_g(wv, g1, g2, o);
#pragma unroll
    for (int k = 0; k < 8; ++k) acc = fmaf(um[k], o[k], acc);

    win_col(pVr1, wlo, whi, wv);          // (G*V) col conv
    conv_g(wv, g1, g2, o);
#pragma unroll
    for (int k = 0; k < 8; ++k) pUw1[PT * k] = o[k];
    FENCE();
    win_row(pU2 - 2, clo, chi, wv);       // *G2 row conv
    conv_q(wv, q1, q2, o);
#pragma unroll
    for (int k = 0; k < 8; ++k) acc = fmaf(um[k], o[k], acc);

    // deterministic reduction: wave shfl tree, then fixed-order per-image sum
#pragma unroll
    for (int off = 32; off > 0; off >>= 1)
        acc += __shfl_down(acc, off, 64);
    if (l == 0) wsum[w] = acc;
    __syncthreads();
    if (t == 0) {
        float sA = ((wsum[0] + wsum[1]) + (wsum[2] + wsum[3]))
                 + ((wsum[4] + wsum[5]) + (wsum[6] + wsum[7]));
        float sB = ((wsum[8] + wsum[9]) + (wsum[10] + wsum[11]))
                 + ((wsum[12] + wsum[13]) + (wsum[14] + wsum[15]));
        partials[2 * blockIdx.x]     = sA;
        partials[2 * blockIdx.x + 1] = sB;
    }
}

extern "C" __global__ void __launch_bounds__(64)
reduce_kernel(const float* __restrict__ partials, float* __restrict__ out)
{
    int t = threadIdx.x;
    float v = partials[t];
#pragma unroll
    for (int off = 32; off > 0; off >>= 1)
        v += __shfl_down(v, off, 64);
    if (t == 0) out[0] = v;
}

extern "C" void kernel_launch(void* const* d_in, const int* in_sizes, int n_in,
                              void* d_out, int out_size, void* d_ws, size_t ws_size,
                              hipStream_t stream)
{
    const float* x    = (const float*)d_in[0];
    const float* y    = (const float*)d_in[1];
    const float* cost = (const float*)d_in[2];
    const float* kern = (const float*)d_in[3];
    float* partials   = (float*)d_ws;   // 64 floats

    sinkhorn_kernel<<<32, 1024, 0, stream>>>(x, y, cost, kern, partials);
    reduce_kernel<<<1, 64, 0, stream>>>(partials, (float*)d_out);
}

// Round 5
// 87.045 us; speedup vs baseline: 1.1867x; 1.1867x over previous
//
#include <hip/hip_runtime.h>

// Sinkhorn (eps=0.2, 50 iters), 64x64 images, b=64. Separable banded Gibbs:
// K = G (x) G, G[i,k]=exp(-5(i-k)^2), radius 2 in fp32. Each K-apply =
// col-conv (along rows) then row-conv (along cols), in LDS.
//
// R5: LDS-issue-bound fix. 64 blocks x 512 thr (8 waves/image, R3 topology —
// R4's 16-wave coupling regressed). Each thread owns a 2x4 tile:
//   col phase: 6x ds_read_b128 + 2x ds_write_b128   (was 12+8 scalar b32)
//   row phase: 8x ds_read_b64  + 2x ds_write_b128   (was 12+8 scalar b32)
// Pitch 68 floats -> every row 16B-aligned. Bank check (32 banks, word addr
// 68r+4tc+..., 68 mod 32 = 4): each 16-lane quarter covers every bank exactly
// twice (2-way = free, m136) for all four access shapes.
// Scratch aliases the destination buffer (dead value); wave w owns rows
// [8w,8w+8) in both phases -> intra-pair handoff is lgkmcnt(0) fence (DS ops
// retire in order per wave), halo crossing needs 2 __syncthreads per iter.

#define PT 68

#define FENCE() asm volatile("s_waitcnt lgkmcnt(0)" ::: "memory")

__device__ __forceinline__ float frcp_nr(float d) {
    float r = __builtin_amdgcn_rcpf(d);
    return r * fmaf(-d, r, 2.0f);   // 1 Newton step: ~1 ulp
}

// conv along row index: read 6 rows x 4 cols (float4, stride PT) from rp,
// write 2 rows x 4 cols to wp. taps (t1,t2), center weight cw (1 for G, 0 for G2).
__device__ __forceinline__ void pass_col(const float* __restrict__ rp,
                                         float* __restrict__ wp,
                                         bool lo, bool hi,
                                         float t1, float t2, float cw)
{
    float W[6][4];
#pragma unroll
    for (int m = 0; m < 6; ++m) {
        float4 f = *(const float4*)(rp + PT * m);
        W[m][0] = f.x; W[m][1] = f.y; W[m][2] = f.z; W[m][3] = f.w;
    }
    if (!lo) {
#pragma unroll
        for (int c = 0; c < 4; ++c) { W[0][c] = 0.f; W[1][c] = 0.f; }
    }
    if (!hi) {
#pragma unroll
        for (int c = 0; c < 4; ++c) { W[4][c] = 0.f; W[5][c] = 0.f; }
    }
    float a0[4], a1[4];
#pragma unroll
    for (int c = 0; c < 4; ++c) {
        a0[c] = fmaf(t2, W[0][c] + W[4][c], fmaf(t1, W[1][c] + W[3][c], cw * W[2][c]));
        a1[c] = fmaf(t2, W[1][c] + W[5][c], fmaf(t1, W[2][c] + W[4][c], cw * W[3][c]));
    }
    *(float4*)(wp)      = make_float4(a0[0], a0[1], a0[2], a0[3]);
    *(float4*)(wp + PT) = make_float4(a1[0], a1[1], a1[2], a1[3]);
}

// conv along col index: read 2 rows x 8 cols (float2 pieces) from rp
// (= tile base - 2 cols), produce 2x4 outputs in o[8].
__device__ __forceinline__ void pass_row(const float* __restrict__ rp,
                                         bool clo, bool chi,
                                         float t1, float t2, float cw,
                                         float* __restrict__ o)
{
    float R[2][8];
#pragma unroll
    for (int row = 0; row < 2; ++row) {
#pragma unroll
        for (int j = 0; j < 4; ++j) {
            float2 f = *(const float2*)(rp + PT * row + 2 * j);
            R[row][2 * j]     = f.x;
            R[row][2 * j + 1] = f.y;
        }
        if (!clo) { R[row][0] = 0.f; R[row][1] = 0.f; }
        if (!chi) { R[row][6] = 0.f; R[row][7] = 0.f; }
    }
#pragma unroll
    for (int row = 0; row < 2; ++row)
#pragma unroll
        for (int c = 0; c < 4; ++c)
            o[4 * row + c] = fmaf(t2, R[row][c] + R[row][c + 4],
                             fmaf(t1, R[row][c + 1] + R[row][c + 3], cw * R[row][c + 2]));
}

extern "C" __global__ void __launch_bounds__(512)
sinkhorn_kernel(const float* __restrict__ x, const float* __restrict__ y,
                const float* __restrict__ cost, const float* __restrict__ kern,
                float* __restrict__ partials)
{
    // [pad144][V 4352][pad144][U 4352][pad144][wsum 8] = 9144 floats (36.6 KB)
    __shared__ __align__(16) float lds[9144];
    float* const V    = lds + 144;
    float* const U    = lds + 4640;
    float* const wsum = lds + 9136;

    const int t  = threadIdx.x;
    const int l  = t & 63;
    const int w  = t >> 6;          // wave 0..7: owns rows [8w, 8w+8)
    const int tc = l & 15;          // col tile 0..15
    const int pr = l >> 4;          // row pair within strip 0..3
    const int r0 = 8 * w + 2 * pr;  // tile rows r0, r0+1
    const int c0 = 4 * tc;          // tile cols c0..c0+3
    const int b  = blockIdx.x;

    const float g1 = kern[(size_t)64  * 4096];        // e^-5
    const float g2 = kern[(size_t)128 * 4096];        // e^-20
    const float q1 = cost[(size_t)64  * 4096] * g1;   // 1*e^-5
    const float q2 = cost[(size_t)128 * 4096] * g2;   // 4*e^-20

    // loop-invariant LDS pointers
    const float* const pVr = V + PT * (r0 - 2) + c0;  // col reads from V
    const float* const pUr = U + PT * (r0 - 2) + c0;  // col reads from U
    float* const pVw = V + PT * r0 + c0;              // writes into V buffer
    float* const pUw = U + PT * r0 + c0;              // writes into U buffer
    const float* const pVq = pVw - 2;                 // row reads from V buffer
    const float* const pUq = pUw - 2;                 // row reads from U buffer

    const bool lo  = (r0 != 0),  hi  = (r0 != 62);    // row-window edges
    const bool clo = (tc != 0),  chi = (tc != 15);    // col-window edges

    // marginals at this thread's tile, registers for all 50 iters
    float xv[8], yv[8];
    {
        const float* xb = x + (size_t)b * 4096 + 64 * r0 + c0;
        const float* yb = y + (size_t)b * 4096 + 64 * r0 + c0;
        float4 f;
        f = *(const float4*)(xb);      xv[0]=f.x; xv[1]=f.y; xv[2]=f.z; xv[3]=f.w;
        f = *(const float4*)(xb + 64); xv[4]=f.x; xv[5]=f.y; xv[6]=f.z; xv[7]=f.w;
        f = *(const float4*)(yb);      yv[0]=f.x; yv[1]=f.y; yv[2]=f.z; yv[3]=f.w;
        f = *(const float4*)(yb + 64); yv[4]=f.x; yv[5]=f.y; yv[6]=f.z; yv[7]=f.w;
    }

    // V init = 1/n
    {
        const float4 ini = make_float4(1.f/4096, 1.f/4096, 1.f/4096, 1.f/4096);
        *(float4*)(pVw)      = ini;
        *(float4*)(pVw + PT) = ini;
    }
    __syncthreads();

    float o[8], um[8];

#pragma unroll 1
    for (int it = 0; it < 50; ++it) {
        // ---- pair 1: S = G*V (scratch in U buffer); U = x / (S*G + 1e-8)
        pass_col(pVr, pUw, lo, hi, g1, g2, 1.0f);
        FENCE();
        pass_row(pUq, clo, chi, g1, g2, 1.0f, o);
#pragma unroll
        for (int k = 0; k < 8; ++k) um[k] = xv[k] * frcp_nr(o[k] + 1e-8f);
        *(float4*)(pUw)      = make_float4(um[0], um[1], um[2], um[3]);
        *(float4*)(pUw + PT) = make_float4(um[4], um[5], um[6], um[7]);
        __syncthreads();

        // ---- pair 2: S = G*U (scratch in V buffer); V = y / (S*G + 1e-8)
        pass_col(pUr, pVw, lo, hi, g1, g2, 1.0f);
        FENCE();
        pass_row(pVq, clo, chi, g1, g2, 1.0f, o);
#pragma unroll
        for (int k = 0; k < 8; ++k) o[k] = yv[k] * frcp_nr(o[k] + 1e-8f);
        *(float4*)(pVw)      = make_float4(o[0], o[1], o[2], o[3]);
        *(float4*)(pVw + PT) = make_float4(o[4], o[5], o[6], o[7]);
        __syncthreads();
    }

    // ---- distance: sum U o (G2*V*G) + sum U o (G*V*G2);  um = final U (regs)
    float acc = 0.0f;

    pass_col(pVr, pUw, lo, hi, q1, q2, 0.0f);    // S = G2*V
    FENCE();
    pass_row(pUq, clo, chi, g1, g2, 1.0f, o);    // (G2*V)*G
#pragma unroll
    for (int k = 0; k < 8; ++k) acc = fmaf(um[k], o[k], acc);

    FENCE();   // drain row reads before scratch overwrite
    pass_col(pVr, pUw, lo, hi, g1, g2, 1.0f);    // S = G*V
    FENCE();
    pass_row(pUq, clo, chi, q1, q2, 0.0f, o);    // (G*V)*G2
#pragma unroll
    for (int k = 0; k < 8; ++k) acc = fmaf(um[k], o[k], acc);

    // deterministic reduction: wave shfl tree, then fixed-order 8-way sum
#pragma unroll
    for (int off = 32; off > 0; off >>= 1)
        acc += __shfl_down(acc, off, 64);
    if (l == 0) wsum[w] = acc;
    __syncthreads();
    if (t == 0) {
        partials[b] = ((wsum[0] + wsum[1]) + (wsum[2] + wsum[3]))
                    + ((wsum[4] + wsum[5]) + (wsum[6] + wsum[7]));
    }
}

extern "C" __global__ void __launch_bounds__(64)
reduce_kernel(const float* __restrict__ partials, float* __restrict__ out)
{
    int t = threadIdx.x;
    float v = partials[t];
#pragma unroll
    for (int off = 32; off > 0; off >>= 1)
        v += __shfl_down(v, off, 64);
    if (t == 0) out[0] = v;
}

extern "C" void kernel_launch(void* const* d_in, const int* in_sizes, int n_in,
                              void* d_out, int out_size, void* d_ws, size_t ws_size,
                              hipStream_t stream)
{
    const float* x    = (const float*)d_in[0];
    const float* y    = (const float*)d_in[1];
    const float* cost = (const float*)d_in[2];
    const float* kern = (const float*)d_in[3];
    float* partials   = (float*)d_ws;   // 64 floats

    sinkhorn_kernel<<<64, 512, 0, stream>>>(x, y, cost, kern, partials);
    reduce_kernel<<<1, 64, 0, stream>>>(partials, (float*)d_out);
}

// Round 6
// 65.242 us; speedup vs baseline: 1.5833x; 1.3342x over previous
//
#include <hip/hip_runtime.h>

// Sinkhorn (eps=0.2, 50 iters), 64x64 images, b=64. Separable banded Gibbs:
// K = G (x) G, G[i,k]=exp(-5(i-k)^2), radius 2 in fp32.
//
// R6: register-resident. V kept column-per-lane (layout-A: lane l holds
// V[8w+k][l]), U row-per-lane (layout-B: lane holds U[8w+q][8hq+c]).
// Using (G*V)*G = G*(V*G): the conv parallel to the register layout is done
// in VALU (vertical for V with halo rows held in regs, computed redundantly;
// horizontal for U with col halos via 4 __shfl). Only the transpose-direction
// conv goes through LDS: 8 b32 writes + 12/16 b32 window reads per pair.
// All LDS shapes are perfect bank permutations per instruction:
//   p1b W: (8w+k+l)%32   p1b R: (8w+l+m-2)%32
//   p2b W: (8w+l+c)%32   p2b R: (8w-4+m+l)%32     -> zero conflicts.
// Hazards: RAW inside p2b covered by barrier beta; cross-iteration WAR
// (p2b reads vs next p1b/p2b writes) covered by barrier alpha at iter start
// (__syncthreads drains lgkmcnt). p1b scratch reads are wave-own rows ->
// lgkmcnt fence. Spill reads (cols/rows out of range) hit pad or neighbor
// cells and are discarded by selects.

#define FENCE() asm volatile("s_waitcnt lgkmcnt(0)" ::: "memory")

__device__ __forceinline__ float frcp_nr(float d) {
    float r = __builtin_amdgcn_rcpf(d);
    return r * fmaf(-d, r, 2.0f);   // 1 Newton step: ~1 ulp
}

extern "C" __global__ void __launch_bounds__(512)
sinkhorn_kernel(const float* __restrict__ x, const float* __restrict__ y,
                const float* __restrict__ cost, const float* __restrict__ kern,
                float* __restrict__ partials)
{
    // [padlo 260][S 65*64][padhi 260][wsum 8] = 4688 floats (18.75 KB)
    __shared__ float lds[4688];
    float* const S    = lds + 260;
    float* const wsum = lds + 4680;

    const int t  = threadIdx.x;
    const int l  = t & 63;
    const int w  = t >> 6;          // wave 0..7 owns rows [8w, 8w+8)
    const int q  = l & 7;
    const int hq = l >> 3;
    const int rB = 8 * w + q;       // layout-B row
    const int c0 = 8 * hq;          // layout-B col base
    const int b  = blockIdx.x;

    const float g1 = kern[(size_t)64  * 4096];        // e^-5
    const float g2 = kern[(size_t)128 * 4096];        // e^-20
    const float q1 = cost[(size_t)64  * 4096] * g1;   // 1*e^-5
    const float q2 = cost[(size_t)128 * 4096] * g2;   // 4*e^-20

    // loop-invariant LDS pointers (all accesses b32 with immediate offsets)
    float* const pSwA = S + 65 * (8 * w) + l;         // p1b writes  [+65k]
    const float* const pSrB = S + 65 * rB + c0 - 2;   // p1b reads   [+m]
    float* const pSwB = S + 65 * rB + c0;             // p2b writes  [+c]
    const float* const pSrA = S + 65 * (8 * w - 4) + l; // p2b reads [+65m]

    const bool lo  = (w > 0),  hi  = (w < 7);
    const bool clo = (hq > 0), chi = (hq < 7);
    const int  lm = (l - 8) & 63, lp = (l + 8) & 63;  // shuffle sources

    // marginals in registers for all 50 iters
    float xv[8], yv[8], yh[4];
    {
        const float* xb = x + (size_t)b * 4096 + 64 * rB + c0;
        float4 f;
        f = *(const float4*)(xb);     xv[0]=f.x; xv[1]=f.y; xv[2]=f.z; xv[3]=f.w;
        f = *(const float4*)(xb + 4); xv[4]=f.x; xv[5]=f.y; xv[6]=f.z; xv[7]=f.w;
        const float* yb = y + (size_t)b * 4096 + l;
#pragma unroll
        for (int k = 0; k < 8; ++k) yv[k] = yb[64 * (8 * w + k)];
        yh[0] = yb[64 * (lo ? 8 * w - 2 : 0)];
        yh[1] = yb[64 * (lo ? 8 * w - 1 : 0)];
        yh[2] = yb[64 * (hi ? 8 * w + 8 : 63)];
        yh[3] = yb[64 * (hi ? 8 * w + 9 : 63)];
    }

    // state: V layout-A (+ halo rows), U layout-B
    float vv[8], vh0, vh1, vh2, vh3, um[8];
#pragma unroll
    for (int k = 0; k < 8; ++k) vv[k] = 1.0f / 4096.0f;
    vh0 = vh1 = vh2 = vh3 = 1.0f / 4096.0f;

    float W[12], R[12], Rv[16], s8[8], o[8], e[12];

#pragma unroll 1
    for (int it = 0; it < 50; ++it) {
        __syncthreads();                       // alpha: WAR across iterations

        // ---- p1a: S = G*V vertical, in registers
        W[0] = lo ? vh0 : 0.f;  W[1] = lo ? vh1 : 0.f;
#pragma unroll
        for (int k = 0; k < 8; ++k) W[k + 2] = vv[k];
        W[10] = hi ? vh2 : 0.f; W[11] = hi ? vh3 : 0.f;
#pragma unroll
        for (int k = 0; k < 8; ++k)
            s8[k] = fmaf(g2, W[k] + W[k + 4], fmaf(g1, W[k + 1] + W[k + 3], W[k + 2]));

        // ---- p1b: transpose + horizontal window; U = x / (S*G + 1e-8)
#pragma unroll
        for (int k = 0; k < 8; ++k) pSwA[65 * k] = s8[k];
        FENCE();
#pragma unroll
        for (int m = 0; m < 12; ++m) R[m] = pSrB[m];
        if (!clo) { R[0] = 0.f; R[1] = 0.f; }
        if (!chi) { R[10] = 0.f; R[11] = 0.f; }
#pragma unroll
        for (int c = 0; c < 8; ++c) {
            o[c] = fmaf(g2, R[c] + R[c + 4], fmaf(g1, R[c + 1] + R[c + 3], R[c + 2]));
            um[c] = xv[c] * frcp_nr(o[c] + 1e-8f);
        }

        // ---- p2a: T = U*G horizontal, in registers (col halos via shuffle)
        {
            float m2 = __shfl(um[6], lm, 64), m1 = __shfl(um[7], lm, 64);
            float p0 = __shfl(um[0], lp, 64), p1 = __shfl(um[1], lp, 64);
            W[0] = clo ? m2 : 0.f;  W[1] = clo ? m1 : 0.f;
#pragma unroll
            for (int c = 0; c < 8; ++c) W[c + 2] = um[c];
            W[10] = chi ? p0 : 0.f; W[11] = chi ? p1 : 0.f;
        }
#pragma unroll
        for (int c = 0; c < 8; ++c)
            s8[c] = fmaf(g2, W[c] + W[c + 4], fmaf(g1, W[c + 1] + W[c + 3], W[c + 2]));

        // ---- p2b: transpose + vertical window; V = y / (G*T + 1e-8)
        //      (also recompute halo rows 8w-2,8w-1,8w+8,8w+9 redundantly)
#pragma unroll
        for (int c = 0; c < 8; ++c) pSwB[c] = s8[c];
        __syncthreads();                       // beta: transpose RAW
#pragma unroll
        for (int m = 0; m < 16; ++m) Rv[m] = pSrA[65 * m];
        if (w == 0) { Rv[0] = Rv[1] = Rv[2] = Rv[3] = 0.f; }
        if (w == 7) { Rv[12] = Rv[13] = Rv[14] = Rv[15] = 0.f; }
#pragma unroll
        for (int k = 0; k < 12; ++k)
            e[k] = fmaf(g2, Rv[k] + Rv[k + 4], fmaf(g1, Rv[k + 1] + Rv[k + 3], Rv[k + 2]));
#pragma unroll
        for (int k = 0; k < 8; ++k) vv[k] = yv[k] * frcp_nr(e[k + 2] + 1e-8f);
        vh0 = yh[0] * frcp_nr(e[0]  + 1e-8f);
        vh1 = yh[1] * frcp_nr(e[1]  + 1e-8f);
        vh2 = yh[2] * frcp_nr(e[10] + 1e-8f);
        vh3 = yh[3] * frcp_nr(e[11] + 1e-8f);
    }

    // ---- distance: sum U o ((G2*V)*G) + sum U o ((G*V)*G2)
    __syncthreads();   // protect S from last p2b reads before epilogue writes
    float acc = 0.0f;

    W[0] = lo ? vh0 : 0.f;  W[1] = lo ? vh1 : 0.f;
#pragma unroll
    for (int k = 0; k < 8; ++k) W[k + 2] = vv[k];
    W[10] = hi ? vh2 : 0.f; W[11] = hi ? vh3 : 0.f;

    // round 1: vertical q-taps, horizontal g-taps
#pragma unroll
    for (int k = 0; k < 8; ++k)
        s8[k] = fmaf(q2, W[k] + W[k + 4], q1 * (W[k + 1] + W[k + 3]));
#pragma unroll
    for (int k = 0; k < 8; ++k) pSwA[65 * k] = s8[k];
    FENCE();
#pragma unroll
    for (int m = 0; m < 12; ++m) R[m] = pSrB[m];
    if (!clo) { R[0] = 0.f; R[1] = 0.f; }
    if (!chi) { R[10] = 0.f; R[11] = 0.f; }
#pragma unroll
    for (int c = 0; c < 8; ++c) {
        o[c] = fmaf(g2, R[c] + R[c + 4], fmaf(g1, R[c + 1] + R[c + 3], R[c + 2]));
        acc = fmaf(um[c], o[c], acc);
    }
    FENCE();   // order round-1 reads before round-2 overwrite (same-wave WAR)

    // round 2: vertical g-taps, horizontal q-taps
#pragma unroll
    for (int k = 0; k < 8; ++k)
        s8[k] = fmaf(g2, W[k] + W[k + 4], fmaf(g1, W[k + 1] + W[k + 3], W[k + 2]));
#pragma unroll
    for (int k = 0; k < 8; ++k) pSwA[65 * k] = s8[k];
    FENCE();
#pragma unroll
    for (int m = 0; m < 12; ++m) R[m] = pSrB[m];
    if (!clo) { R[0] = 0.f; R[1] = 0.f; }
    if (!chi) { R[10] = 0.f; R[11] = 0.f; }
#pragma unroll
    for (int c = 0; c < 8; ++c) {
        o[c] = fmaf(q2, R[c] + R[c + 4], q1 * (R[c + 1] + R[c + 3]));
        acc = fmaf(um[c], o[c], acc);
    }

    // deterministic reduction: wave shfl tree, then fixed-order 8-way sum
#pragma unroll
    for (int off = 32; off > 0; off >>= 1)
        acc += __shfl_down(acc, off, 64);
    if (l == 0) wsum[w] = acc;
    __syncthreads();
    if (t == 0) {
        partials[b] = ((wsum[0] + wsum[1]) + (wsum[2] + wsum[3]))
                    + ((wsum[4] + wsum[5]) + (wsum[6] + wsum[7]));
    }
}

extern "C" __global__ void __launch_bounds__(64)
reduce_kernel(const float* __restrict__ partials, float* __restrict__ out)
{
    int t = threadIdx.x;
    float v = partials[t];
#pragma unroll
    for (int off = 32; off > 0; off >>= 1)
        v += __shfl_down(v, off, 64);
    if (t == 0) out[0] = v;
}

extern "C" void kernel_launch(void* const* d_in, const int* in_sizes, int n_in,
                              void* d_out, int out_size, void* d_ws, size_t ws_size,
                              hipStream_t stream)
{
    const float* x    = (const float*)d_in[0];
    const float* y    = (const float*)d_in[1];
    const float* cost = (const float*)d_in[2];
    const float* kern = (const float*)d_in[3];
    float* partials   = (float*)d_ws;   // 64 floats

    sinkhorn_kernel<<<64, 512, 0, stream>>>(x, y, cost, kern, partials);
    reduce_kernel<<<1, 64, 0, stream>>>(partials, (float*)d_out);
}